// Round 14
// baseline (309.108 us; speedup 1.0000x reference)
//
#include <hip/hip_runtime.h>

#define HH 2160
#define WW 3840
#define NPIX (HH * WW)

// ---------------------------------------------------------------------------
// Kernel 1: fp32 inverse of pose_cur -- verified-passing configuration
// (OpenBLAS recursive getrf + trsm w/ pre-inverted diagonal + FMA).
// 1-thread kernel: private-array scratch is harmless here (R1-measured).
// ---------------------------------------------------------------------------
__global__ void prep_kernel(const float* __restrict__ pose_last,
                            const float* __restrict__ pose_cur,
                            float* __restrict__ minv,    // 16 floats
                            float* __restrict__ reg_out) {
#pragma clang fp contract(off)
    if (threadIdx.x != 0 || blockIdx.x != 0) return;

    float A[4][4];
    for (int r = 0; r < 4; ++r)
        for (int c = 0; c < 4; ++c)
            A[r][c] = pose_cur[r * 4 + c];

    int ipiv[4];
    {
        int p = 0; float mx = fabsf(A[0][0]);
        for (int i = 1; i < 4; ++i) { float v = fabsf(A[i][0]); if (v > mx) { mx = v; p = i; } }
        ipiv[0] = p;
        if (p != 0) for (int c = 0; c < 4; ++c) { float t = A[0][c]; A[0][c] = A[p][c]; A[p][c] = t; }
        float rp = 1.0f / A[0][0];
        for (int i = 1; i < 4; ++i) A[i][0] = A[i][0] * rp;
    }
    for (int i = 1; i < 4; ++i) {
        float prod = A[i][0] * A[0][1];
        A[i][1] = A[i][1] - prod;
    }
    {
        int p = 1; float mx = fabsf(A[1][1]);
        for (int i = 2; i < 4; ++i) { float v = fabsf(A[i][1]); if (v > mx) { mx = v; p = i; } }
        ipiv[1] = p;
        if (p != 1) for (int c = 0; c < 4; ++c) { float t = A[1][c]; A[1][c] = A[p][c]; A[p][c] = t; }
        float rp = 1.0f / A[1][1];
        for (int i = 2; i < 4; ++i) A[i][1] = A[i][1] * rp;
    }
    for (int k = 2; k < 4; ++k)
        A[1][k] = fmaf(-A[1][0], A[0][k], A[1][k]);
    for (int i = 2; i < 4; ++i)
        for (int j = 2; j < 4; ++j) {
            float acc = A[i][0] * A[0][j];
            acc = fmaf(A[i][1], A[1][j], acc);
            A[i][j] = A[i][j] - acc;
        }
    {
        int p = 2; float mx = fabsf(A[2][2]);
        { float v = fabsf(A[3][2]); if (v > mx) { mx = v; p = 3; } }
        ipiv[2] = p;
        if (p != 2) for (int c = 0; c < 4; ++c) { float t = A[2][c]; A[2][c] = A[p][c]; A[p][c] = t; }
        float rp = 1.0f / A[2][2];
        A[3][2] = A[3][2] * rp;
    }
    {
        float prod = A[3][2] * A[2][3];
        A[3][3] = A[3][3] - prod;
    }
    ipiv[3] = 3;

    float B[4][4];
    for (int r = 0; r < 4; ++r)
        for (int c = 0; c < 4; ++c)
            B[r][c] = (r == c) ? 1.f : 0.f;
    for (int j = 0; j < 4; ++j) {
        int p = ipiv[j];
        if (p != j)
            for (int c = 0; c < 4; ++c) { float t = B[j][c]; B[j][c] = B[p][c]; B[p][c] = t; }
    }
    for (int j = 0; j < 4; ++j)
        for (int k = 0; k < 4; ++k) {
            float t = B[k][j];
            if (t != 0.f)
                for (int i = k + 1; i < 4; ++i)
                    B[i][j] = fmaf(-t, A[i][k], B[i][j]);
        }
    float ainv[4];
    for (int k = 0; k < 4; ++k) ainv[k] = 1.0f / A[k][k];
    for (int j = 0; j < 4; ++j)
        for (int k = 3; k >= 0; --k) {
            if (B[k][j] != 0.f) {
                B[k][j] = B[k][j] * ainv[k];
                float t = B[k][j];
                for (int i = 0; i < k; ++i)
                    B[i][j] = fmaf(-t, A[i][k], B[i][j]);
            }
        }

    for (int r = 0; r < 4; ++r)
        for (int c = 0; c < 4; ++c) minv[r * 4 + c] = B[r][c];

    float reg = 0.f;
    for (int i = 0; i < 16; ++i) {
        float d = pose_cur[i] - pose_last[i];
        reg = reg + d * d;
    }
    *reg_out = reg;
}

// per-pixel m22 selection (calibrated q = 379/1024 mix)
__device__ __forceinline__ float select_m22(unsigned j, float m22_base) {
    unsigned hsh = j * 2654435761u;
    if (((hsh >> 16) & 1023u) < 379u)
        return __int_as_float(__float_as_int(m22_base) + 1);
    return m22_base;
}

// full per-pixel chain (bit-identical everywhere it's used)
__device__ __forceinline__ void project_chain(
        int gx, int gy, float Z, const float* __restrict__ P,
        const float* __restrict__ minv, float m22,
        float fx, float cxx, float fy, float cyy,
        int* u_out, int* v_out, float* pz_out) {
#pragma clang fp contract(off)
    float xg = (float)gx - cxx;
    float yg = (float)gy - cyy;
    float X = xg * Z / fx;
    float Y = yg * Z / fy;
    float wx = X * P[0] + Y * P[4] + Z * P[8]  + P[12];
    float wy = X * P[1] + Y * P[5] + Z * P[9]  + P[13];
    float wz = X * P[2] + Y * P[6] + Z * P[10] + P[14];
    float wk = X * P[3] + Y * P[7] + Z * P[11] + P[15];
    float px = wx * minv[0] + wy * minv[4] + wz * minv[8]  + wk * minv[12];
    float py = wx * minv[1] + wy * minv[5] + wz * minv[9]  + wk * minv[13];
    float pz = wx * minv[2] + wy * minv[6] + wz * m22      + wk * minv[14];
    *u_out = (int)(px / pz * fx + cxx);   // trunc toward zero
    *v_out = (int)(py / pz * fy + cyy);
    *pz_out = pz;
}

// ---------------------------------------------------------------------------
// Kernel 2 (R14 change: TRANSPOSED atomic-phase mapping): scatter runs at
// 59 G atomics/s with VALU 44% / HBM 23% -- neither pipe saturated. Theory:
// per-64B-line serialization at the coherence point (old mapping: a wave =
// 4 rows x 16 consecutive cols -> ~16 lanes' targets share one line).
// New mapping for the proj_last phase ONLY: wave = 4 cols x 16 rows ->
// ~4 lanes/line (4x fewer line conflicts). atomicMax is thread/order-
// independent -> semantics identical; the proj_cur LDS-table phase keeps
// the original mapping. depth_last reads become column-strided but the
// block still touches the same 16 lines (L1 absorbs it).
// ---------------------------------------------------------------------------
__global__ __launch_bounds__(256) void scatter_kernel(
        const float* __restrict__ depth_last,
        const float* __restrict__ depth_cur,
        const float* __restrict__ intr,
        const float* __restrict__ pose_last,
        const float* __restrict__ pose_cur,
        const float* __restrict__ minv,
        unsigned* __restrict__ keys_last,
        float* __restrict__ proj_cur) {
    const float fx = intr[0], cxx = intr[2], fy = intr[4], cyy = intr[5];
    const float m22base = minv[10];

    __shared__ int   lds_tgt[289];   // 17x17 target slot (-1 = none)
    __shared__ float lds_z[289];

    const int bx = blockIdx.x * 16, by = blockIdx.y * 16;
    const int tx = threadIdx.x & 15, ty = threadIdx.x >> 4;
    const int gx = bx + tx, gy = by + ty;
    const int j  = gy * WW + gx;

    // own-pixel proj_last scatter, TRANSPOSED mapping (issue first)
    {
        const int gx2 = bx + (threadIdx.x >> 4);   // column 0..15
        const int gy2 = by + (threadIdx.x & 15);   // row    0..15
        const int j2  = gy2 * WW + gx2;
        float Z = depth_last[j2];
        float m22 = select_m22((unsigned)j2, m22base);
        int u, v; float pz;
        project_chain(gx2, gy2, Z, pose_last, minv, m22, fx, cxx, fy, cyy, &u, &v, &pz);
        if (u >= 0 && u < WW && v >= 0 && v < HH)
            atomicMax(&keys_last[v * WW + u], (unsigned)j2 + 1u);
    }

    // fill 17x17 cur-chain table (tile + right/bottom halo)
    for (int li = threadIdx.x; li < 289; li += 256) {
        int lx = li % 17, ly = li / 17;
        int gx0 = bx + lx, gy0 = by + ly;
        int tgt = -1; float zval = 0.f;
        if (gx0 < WW && gy0 < HH) {
            int j0 = gy0 * WW + gx0;
            float Z = depth_cur[j0];
            float m22 = select_m22((unsigned)j0, m22base);
            int u, v; float pz;
            project_chain(gx0, gy0, Z, pose_cur, minv, m22, fx, cxx, fy, cyy, &u, &v, &pz);
            if (u >= 0 && u < WW && v >= 0 && v < HH) tgt = v * WW + u;
            zval = pz;
        }
        lds_tgt[li] = tgt;
        lds_z[li]   = zval;
    }
    __syncthreads();

    // slot resolution: candidates in descending source-j order (last-wins)
    float pc = 0.f;
    bool found = false;
#pragma unroll
    for (int c = 0; c < 4; ++c) {
        int dy = (c < 2) ? 1 : 0;
        int dx = (c == 0 || c == 2) ? 1 : 0;
        if (!found && gy + dy < HH && gx + dx < WW) {
            int li = (ty + dy) * 17 + (tx + dx);
            if (lds_tgt[li] == j) { pc = lds_z[li]; found = true; }
        }
    }
    proj_cur[j] = pc;
}

// bit-identical recompute of the winner's pz (same op order as scatter)
__device__ __forceinline__ float recompute_pz(
        unsigned j, const float* __restrict__ depth,
        const float* __restrict__ P, const float* __restrict__ minv,
        float fx, float cxx, float fy, float cyy) {
#pragma clang fp contract(off)
    int gy = (int)(j / (unsigned)WW);
    int gx = (int)j - gy * WW;
    float xg = (float)gx - cxx;
    float yg = (float)gy - cyy;
    float Z = depth[j];
    float m22 = select_m22(j, minv[10]);
    float X = xg * Z / fx;
    float Y = yg * Z / fy;
    float wx = X * P[0] + Y * P[4] + Z * P[8]  + P[12];
    float wy = X * P[1] + Y * P[5] + Z * P[9]  + P[13];
    float wz = X * P[2] + Y * P[6] + Z * P[10] + P[14];
    float wk = X * P[3] + Y * P[7] + Z * P[11] + P[15];
    return wx * minv[2] + wy * minv[6] + wz * m22 + wk * minv[14];
}

// ---------------------------------------------------------------------------
// Kernel 3 (verified R13, XCD-banded): block b serves horizontal band
// (b & 7) == its XCD under round-robin dispatch -> each band's gathered
// depth_last slice (~4.1 MB) fits one XCD's 4 MiB L2 (R13: -14us).
// ---------------------------------------------------------------------------
__global__ __launch_bounds__(256) void reduce_kernel(
        const unsigned* __restrict__ keys_last,
        const float* __restrict__ proj_cur,
        const float* __restrict__ depth_last,
        const float* __restrict__ depth_cur,
        const float* __restrict__ intr,
        const float* __restrict__ pose_last,
        const float* __restrict__ minv,
        double* __restrict__ accum) {
    const float fx = intr[0], cxx = intr[2], fy = intr[4], cyy = intr[5];
    const uint4*  k4 = (const uint4*)keys_last;
    const float4* p4 = (const float4*)proj_cur;
    const float4* d4 = (const float4*)depth_cur;
    const int nq = NPIX / 4;          // 2,073,600 exact
    const int qpb = nq / 8;           // quads per band = 259,200 exact
    const int band = blockIdx.x & 7;  // XCD under round-robin dispatch
    const int lb   = blockIdx.x >> 3; // block index within band (0..255)
    const int qStart = band * qpb;
    const int qEnd   = qStart + qpb;
    const int bandStride = (gridDim.x >> 3) * blockDim.x;  // 65,536

    double acc = 0.0;
    for (int q = qStart + lb * blockDim.x + threadIdx.x; q < qEnd; q += bandStride) {
        uint4  kl = k4[q];
        float4 pc = p4[q];
        float4 dc = d4[q];
        {
            float pl = kl.x ? recompute_pz(kl.x - 1u, depth_last, pose_last, minv, fx, cxx, fy, cyy) : 0.f;
            float mn = fminf(pl, pc.x), mx = fmaxf(pl, pc.x);
            float comb = (mn == 0.0f) ? mx : mn;
            double d = (double)comb - (double)dc.x;
            acc += d * d;
        }
        {
            float pl = kl.y ? recompute_pz(kl.y - 1u, depth_last, pose_last, minv, fx, cxx, fy, cyy) : 0.f;
            float mn = fminf(pl, pc.y), mx = fmaxf(pl, pc.y);
            float comb = (mn == 0.0f) ? mx : mn;
            double d = (double)comb - (double)dc.y;
            acc += d * d;
        }
        {
            float pl = kl.z ? recompute_pz(kl.z - 1u, depth_last, pose_last, minv, fx, cxx, fy, cyy) : 0.f;
            float mn = fminf(pl, pc.z), mx = fmaxf(pl, pc.z);
            float comb = (mn == 0.0f) ? mx : mn;
            double d = (double)comb - (double)dc.z;
            acc += d * d;
        }
        {
            float pl = kl.w ? recompute_pz(kl.w - 1u, depth_last, pose_last, minv, fx, cxx, fy, cyy) : 0.f;
            float mn = fminf(pl, pc.w), mx = fmaxf(pl, pc.w);
            float comb = (mn == 0.0f) ? mx : mn;
            double d = (double)comb - (double)dc.w;
            acc += d * d;
        }
    }
#pragma unroll
    for (int off = 32; off > 0; off >>= 1)
        acc += __shfl_down(acc, off, 64);
    __shared__ double wsum[4];
    int lane = threadIdx.x & 63;
    int wid  = threadIdx.x >> 6;
    if (lane == 0) wsum[wid] = acc;
    __syncthreads();
    if (threadIdx.x == 0) {
        double s = wsum[0] + wsum[1] + wsum[2] + wsum[3];
        atomicAdd(accum, s);
    }
}

__global__ void finalize_kernel(const double* __restrict__ accum,
                                const float* __restrict__ reg,
                                float* __restrict__ out) {
    if (threadIdx.x == 0 && blockIdx.x == 0) {
        double mse = *accum / (double)NPIX;
        out[0] = (float)(mse + 0.001 * (double)(*reg));
    }
}

extern "C" void kernel_launch(void* const* d_in, const int* in_sizes, int n_in,
                              void* d_out, int out_size, void* d_ws, size_t ws_size,
                              hipStream_t stream) {
    const float* depth_last = (const float*)d_in[0];
    const float* depth_cur  = (const float*)d_in[1];
    const float* intr       = (const float*)d_in[2];
    const float* pose_last  = (const float*)d_in[3];
    const float* pose_cur   = (const float*)d_in[4];
    float* out = (float*)d_out;

    char* ws = (char*)d_ws;
    unsigned* keys_last = (unsigned*)ws;                       // NPIX u32
    size_t off1   = (size_t)NPIX * 4;
    double* accum = (double*)(ws + off1);                      // 8 B
    float*  minv  = (float*)(ws + off1 + 8);                   // 64 B
    float*  reg_o = (float*)(ws + off1 + 8 + 64);              // 4 B
    float*  projc = (float*)(ws + off1 + 128);                 // NPIX f32 (128-aligned)

    // zero keys_last + accum only (proj_cur is fully overwritten)
    hipMemsetAsync(d_ws, 0, off1 + 8, stream);

    prep_kernel<<<1, 64, 0, stream>>>(pose_last, pose_cur, minv, reg_o);

    dim3 sgrid(WW / 16, HH / 16);   // 240 x 135, exact tiling
    scatter_kernel<<<sgrid, 256, 0, stream>>>(
        depth_last, depth_cur, intr, pose_last, pose_cur, minv,
        keys_last, projc);

    reduce_kernel<<<2048, 256, 0, stream>>>(
        keys_last, projc, depth_last, depth_cur, intr,
        pose_last, minv, accum);

    finalize_kernel<<<1, 64, 0, stream>>>(accum, reg_o, out);
}

// Round 15
// 293.075 us; speedup vs baseline: 1.0547x; 1.0547x over previous
//
#include <hip/hip_runtime.h>

#define HH 2160
#define WW 3840
#define NPIX (HH * WW)

// ---------------------------------------------------------------------------
// Kernel 1: fp32 inverse of pose_cur -- verified-passing configuration
// (OpenBLAS recursive getrf + trsm w/ pre-inverted diagonal + FMA).
// 1-thread kernel: private-array scratch is harmless here (R1-measured).
// ---------------------------------------------------------------------------
__global__ void prep_kernel(const float* __restrict__ pose_last,
                            const float* __restrict__ pose_cur,
                            float* __restrict__ minv,    // 16 floats
                            float* __restrict__ reg_out) {
#pragma clang fp contract(off)
    if (threadIdx.x != 0 || blockIdx.x != 0) return;

    float A[4][4];
    for (int r = 0; r < 4; ++r)
        for (int c = 0; c < 4; ++c)
            A[r][c] = pose_cur[r * 4 + c];

    int ipiv[4];
    {
        int p = 0; float mx = fabsf(A[0][0]);
        for (int i = 1; i < 4; ++i) { float v = fabsf(A[i][0]); if (v > mx) { mx = v; p = i; } }
        ipiv[0] = p;
        if (p != 0) for (int c = 0; c < 4; ++c) { float t = A[0][c]; A[0][c] = A[p][c]; A[p][c] = t; }
        float rp = 1.0f / A[0][0];
        for (int i = 1; i < 4; ++i) A[i][0] = A[i][0] * rp;
    }
    for (int i = 1; i < 4; ++i) {
        float prod = A[i][0] * A[0][1];
        A[i][1] = A[i][1] - prod;
    }
    {
        int p = 1; float mx = fabsf(A[1][1]);
        for (int i = 2; i < 4; ++i) { float v = fabsf(A[i][1]); if (v > mx) { mx = v; p = i; } }
        ipiv[1] = p;
        if (p != 1) for (int c = 0; c < 4; ++c) { float t = A[1][c]; A[1][c] = A[p][c]; A[p][c] = t; }
        float rp = 1.0f / A[1][1];
        for (int i = 2; i < 4; ++i) A[i][1] = A[i][1] * rp;
    }
    for (int k = 2; k < 4; ++k)
        A[1][k] = fmaf(-A[1][0], A[0][k], A[1][k]);
    for (int i = 2; i < 4; ++i)
        for (int j = 2; j < 4; ++j) {
            float acc = A[i][0] * A[0][j];
            acc = fmaf(A[i][1], A[1][j], acc);
            A[i][j] = A[i][j] - acc;
        }
    {
        int p = 2; float mx = fabsf(A[2][2]);
        { float v = fabsf(A[3][2]); if (v > mx) { mx = v; p = 3; } }
        ipiv[2] = p;
        if (p != 2) for (int c = 0; c < 4; ++c) { float t = A[2][c]; A[2][c] = A[p][c]; A[p][c] = t; }
        float rp = 1.0f / A[2][2];
        A[3][2] = A[3][2] * rp;
    }
    {
        float prod = A[3][2] * A[2][3];
        A[3][3] = A[3][3] - prod;
    }
    ipiv[3] = 3;

    float B[4][4];
    for (int r = 0; r < 4; ++r)
        for (int c = 0; c < 4; ++c)
            B[r][c] = (r == c) ? 1.f : 0.f;
    for (int j = 0; j < 4; ++j) {
        int p = ipiv[j];
        if (p != j)
            for (int c = 0; c < 4; ++c) { float t = B[j][c]; B[j][c] = B[p][c]; B[p][c] = t; }
    }
    for (int j = 0; j < 4; ++j)
        for (int k = 0; k < 4; ++k) {
            float t = B[k][j];
            if (t != 0.f)
                for (int i = k + 1; i < 4; ++i)
                    B[i][j] = fmaf(-t, A[i][k], B[i][j]);
        }
    float ainv[4];
    for (int k = 0; k < 4; ++k) ainv[k] = 1.0f / A[k][k];
    for (int j = 0; j < 4; ++j)
        for (int k = 3; k >= 0; --k) {
            if (B[k][j] != 0.f) {
                B[k][j] = B[k][j] * ainv[k];
                float t = B[k][j];
                for (int i = 0; i < k; ++i)
                    B[i][j] = fmaf(-t, A[i][k], B[i][j]);
            }
        }

    for (int r = 0; r < 4; ++r)
        for (int c = 0; c < 4; ++c) minv[r * 4 + c] = B[r][c];

    float reg = 0.f;
    for (int i = 0; i < 16; ++i) {
        float d = pose_cur[i] - pose_last[i];
        reg = reg + d * d;
    }
    *reg_out = reg;
}

// per-pixel m22 selection (calibrated q = 379/1024 mix)
__device__ __forceinline__ float select_m22(unsigned j, float m22_base) {
    unsigned hsh = j * 2654435761u;
    if (((hsh >> 16) & 1023u) < 379u)
        return __int_as_float(__float_as_int(m22_base) + 1);
    return m22_base;
}

// full per-pixel chain (bit-identical everywhere it's used)
__device__ __forceinline__ void project_chain(
        int gx, int gy, float Z, const float* __restrict__ P,
        const float* __restrict__ minv, float m22,
        float fx, float cxx, float fy, float cyy,
        int* u_out, int* v_out, float* pz_out) {
#pragma clang fp contract(off)
    float xg = (float)gx - cxx;
    float yg = (float)gy - cyy;
    float X = xg * Z / fx;
    float Y = yg * Z / fy;
    float wx = X * P[0] + Y * P[4] + Z * P[8]  + P[12];
    float wy = X * P[1] + Y * P[5] + Z * P[9]  + P[13];
    float wz = X * P[2] + Y * P[6] + Z * P[10] + P[14];
    float wk = X * P[3] + Y * P[7] + Z * P[11] + P[15];
    float px = wx * minv[0] + wy * minv[4] + wz * minv[8]  + wk * minv[12];
    float py = wx * minv[1] + wy * minv[5] + wz * minv[9]  + wk * minv[13];
    float pz = wx * minv[2] + wy * minv[6] + wz * m22      + wk * minv[14];
    *u_out = (int)(px / pz * fx + cxx);   // trunc toward zero
    *v_out = (int)(py / pz * fy + cyy);
    *pz_out = pz;
}

// ---------------------------------------------------------------------------
// Kernel 2 (R15 change: 64x4 TILE): R14 proved spreading atomic targets
// across more lines HURTS (140->174, WRITE +22MB) -> clustering helps.
// A 64x4 tile makes each wave = 1 source row x 64 consecutive cols:
// (a) atomic targets span ~2-3 v-rows instead of ~6 (parallax jitter
// +-4..40px unchanged) -> ~25% fewer dirty lines per wave;
// (b) depth_last / depth_cur loads and proj_cur stores perfectly
// 64-coalesced; (c) identical gather semantics (du,dv in (-1,1) =>
// candidates {u,u+1}x{v,v+1}, halo table 65x5). atomicMax unordered ->
// semantics identical to R13.
// ---------------------------------------------------------------------------
__global__ __launch_bounds__(256) void scatter_kernel(
        const float* __restrict__ depth_last,
        const float* __restrict__ depth_cur,
        const float* __restrict__ intr,
        const float* __restrict__ pose_last,
        const float* __restrict__ pose_cur,
        const float* __restrict__ minv,
        unsigned* __restrict__ keys_last,
        float* __restrict__ proj_cur) {
    const float fx = intr[0], cxx = intr[2], fy = intr[4], cyy = intr[5];
    const float m22base = minv[10];

    __shared__ int   lds_tgt[325];   // 65x5 target slot (-1 = none)
    __shared__ float lds_z[325];

    const int bx = blockIdx.x * 64, by = blockIdx.y * 4;
    const int tx = threadIdx.x & 63, ty = threadIdx.x >> 6;
    const int gx = bx + tx, gy = by + ty;
    const int j  = gy * WW + gx;

    // own-pixel proj_last scatter (independent of LDS; issue first)
    {
        float Z = depth_last[j];
        float m22 = select_m22((unsigned)j, m22base);
        int u, v; float pz;
        project_chain(gx, gy, Z, pose_last, minv, m22, fx, cxx, fy, cyy, &u, &v, &pz);
        if (u >= 0 && u < WW && v >= 0 && v < HH)
            atomicMax(&keys_last[v * WW + u], (unsigned)j + 1u);
    }

    // fill 65x5 cur-chain table (tile + right/bottom halo)
    for (int li = threadIdx.x; li < 325; li += 256) {
        int lx = li % 65, ly = li / 65;
        int gx0 = bx + lx, gy0 = by + ly;
        int tgt = -1; float zval = 0.f;
        if (gx0 < WW && gy0 < HH) {
            int j0 = gy0 * WW + gx0;
            float Z = depth_cur[j0];
            float m22 = select_m22((unsigned)j0, m22base);
            int u, v; float pz;
            project_chain(gx0, gy0, Z, pose_cur, minv, m22, fx, cxx, fy, cyy, &u, &v, &pz);
            if (u >= 0 && u < WW && v >= 0 && v < HH) tgt = v * WW + u;
            zval = pz;
        }
        lds_tgt[li] = tgt;
        lds_z[li]   = zval;
    }
    __syncthreads();

    // slot resolution: candidates in descending source-j order (last-wins)
    float pc = 0.f;
    bool found = false;
#pragma unroll
    for (int c = 0; c < 4; ++c) {
        int dy = (c < 2) ? 1 : 0;
        int dx = (c == 0 || c == 2) ? 1 : 0;
        if (!found && gy + dy < HH && gx + dx < WW) {
            int li = (ty + dy) * 65 + (tx + dx);
            if (lds_tgt[li] == j) { pc = lds_z[li]; found = true; }
        }
    }
    proj_cur[j] = pc;
}

// bit-identical recompute of the winner's pz (same op order as scatter)
__device__ __forceinline__ float recompute_pz(
        unsigned j, const float* __restrict__ depth,
        const float* __restrict__ P, const float* __restrict__ minv,
        float fx, float cxx, float fy, float cyy) {
#pragma clang fp contract(off)
    int gy = (int)(j / (unsigned)WW);
    int gx = (int)j - gy * WW;
    float xg = (float)gx - cxx;
    float yg = (float)gy - cyy;
    float Z = depth[j];
    float m22 = select_m22(j, minv[10]);
    float X = xg * Z / fx;
    float Y = yg * Z / fy;
    float wx = X * P[0] + Y * P[4] + Z * P[8]  + P[12];
    float wy = X * P[1] + Y * P[5] + Z * P[9]  + P[13];
    float wz = X * P[2] + Y * P[6] + Z * P[10] + P[14];
    float wk = X * P[3] + Y * P[7] + Z * P[11] + P[15];
    return wx * minv[2] + wy * minv[6] + wz * m22 + wk * minv[14];
}

// ---------------------------------------------------------------------------
// Kernel 3 (verified R13, XCD-banded): block b serves horizontal band
// (b & 7) == its XCD under round-robin dispatch -> each band's gathered
// depth_last slice (~4.1 MB) fits one XCD's 4 MiB L2 (R13: -14us).
// ---------------------------------------------------------------------------
__global__ __launch_bounds__(256) void reduce_kernel(
        const unsigned* __restrict__ keys_last,
        const float* __restrict__ proj_cur,
        const float* __restrict__ depth_last,
        const float* __restrict__ depth_cur,
        const float* __restrict__ intr,
        const float* __restrict__ pose_last,
        const float* __restrict__ minv,
        double* __restrict__ accum) {
    const float fx = intr[0], cxx = intr[2], fy = intr[4], cyy = intr[5];
    const uint4*  k4 = (const uint4*)keys_last;
    const float4* p4 = (const float4*)proj_cur;
    const float4* d4 = (const float4*)depth_cur;
    const int nq = NPIX / 4;          // 2,073,600 exact
    const int qpb = nq / 8;           // quads per band = 259,200 exact
    const int band = blockIdx.x & 7;  // XCD under round-robin dispatch
    const int lb   = blockIdx.x >> 3; // block index within band (0..255)
    const int qStart = band * qpb;
    const int qEnd   = qStart + qpb;
    const int bandStride = (gridDim.x >> 3) * blockDim.x;  // 65,536

    double acc = 0.0;
    for (int q = qStart + lb * blockDim.x + threadIdx.x; q < qEnd; q += bandStride) {
        uint4  kl = k4[q];
        float4 pc = p4[q];
        float4 dc = d4[q];
        {
            float pl = kl.x ? recompute_pz(kl.x - 1u, depth_last, pose_last, minv, fx, cxx, fy, cyy) : 0.f;
            float mn = fminf(pl, pc.x), mx = fmaxf(pl, pc.x);
            float comb = (mn == 0.0f) ? mx : mn;
            double d = (double)comb - (double)dc.x;
            acc += d * d;
        }
        {
            float pl = kl.y ? recompute_pz(kl.y - 1u, depth_last, pose_last, minv, fx, cxx, fy, cyy) : 0.f;
            float mn = fminf(pl, pc.y), mx = fmaxf(pl, pc.y);
            float comb = (mn == 0.0f) ? mx : mn;
            double d = (double)comb - (double)dc.y;
            acc += d * d;
        }
        {
            float pl = kl.z ? recompute_pz(kl.z - 1u, depth_last, pose_last, minv, fx, cxx, fy, cyy) : 0.f;
            float mn = fminf(pl, pc.z), mx = fmaxf(pl, pc.z);
            float comb = (mn == 0.0f) ? mx : mn;
            double d = (double)comb - (double)dc.z;
            acc += d * d;
        }
        {
            float pl = kl.w ? recompute_pz(kl.w - 1u, depth_last, pose_last, minv, fx, cxx, fy, cyy) : 0.f;
            float mn = fminf(pl, pc.w), mx = fmaxf(pl, pc.w);
            float comb = (mn == 0.0f) ? mx : mn;
            double d = (double)comb - (double)dc.w;
            acc += d * d;
        }
    }
#pragma unroll
    for (int off = 32; off > 0; off >>= 1)
        acc += __shfl_down(acc, off, 64);
    __shared__ double wsum[4];
    int lane = threadIdx.x & 63;
    int wid  = threadIdx.x >> 6;
    if (lane == 0) wsum[wid] = acc;
    __syncthreads();
    if (threadIdx.x == 0) {
        double s = wsum[0] + wsum[1] + wsum[2] + wsum[3];
        atomicAdd(accum, s);
    }
}

__global__ void finalize_kernel(const double* __restrict__ accum,
                                const float* __restrict__ reg,
                                float* __restrict__ out) {
    if (threadIdx.x == 0 && blockIdx.x == 0) {
        double mse = *accum / (double)NPIX;
        out[0] = (float)(mse + 0.001 * (double)(*reg));
    }
}

extern "C" void kernel_launch(void* const* d_in, const int* in_sizes, int n_in,
                              void* d_out, int out_size, void* d_ws, size_t ws_size,
                              hipStream_t stream) {
    const float* depth_last = (const float*)d_in[0];
    const float* depth_cur  = (const float*)d_in[1];
    const float* intr       = (const float*)d_in[2];
    const float* pose_last  = (const float*)d_in[3];
    const float* pose_cur   = (const float*)d_in[4];
    float* out = (float*)d_out;

    char* ws = (char*)d_ws;
    unsigned* keys_last = (unsigned*)ws;                       // NPIX u32
    size_t off1   = (size_t)NPIX * 4;
    double* accum = (double*)(ws + off1);                      // 8 B
    float*  minv  = (float*)(ws + off1 + 8);                   // 64 B
    float*  reg_o = (float*)(ws + off1 + 8 + 64);              // 4 B
    float*  projc = (float*)(ws + off1 + 128);                 // NPIX f32 (128-aligned)

    // zero keys_last + accum only (proj_cur is fully overwritten)
    hipMemsetAsync(d_ws, 0, off1 + 8, stream);

    prep_kernel<<<1, 64, 0, stream>>>(pose_last, pose_cur, minv, reg_o);

    dim3 sgrid(WW / 64, HH / 4);    // 60 x 540, exact tiling
    scatter_kernel<<<sgrid, 256, 0, stream>>>(
        depth_last, depth_cur, intr, pose_last, pose_cur, minv,
        keys_last, projc);

    reduce_kernel<<<2048, 256, 0, stream>>>(
        keys_last, projc, depth_last, depth_cur, intr,
        pose_last, minv, accum);

    finalize_kernel<<<1, 64, 0, stream>>>(accum, reg_o, out);
}

// Round 16
// 283.581 us; speedup vs baseline: 1.0900x; 1.0335x over previous
//
#include <hip/hip_runtime.h>

#define HH 2160
#define WW 3840
#define NPIX (HH * WW)

// ---------------------------------------------------------------------------
// Kernel 1: fp32 inverse of pose_cur -- verified-passing configuration
// (OpenBLAS recursive getrf + trsm w/ pre-inverted diagonal + FMA).
// 1-thread kernel: private-array scratch is harmless here (R1-measured).
// ---------------------------------------------------------------------------
__global__ void prep_kernel(const float* __restrict__ pose_last,
                            const float* __restrict__ pose_cur,
                            float* __restrict__ minv,    // 16 floats
                            float* __restrict__ reg_out) {
#pragma clang fp contract(off)
    if (threadIdx.x != 0 || blockIdx.x != 0) return;

    float A[4][4];
    for (int r = 0; r < 4; ++r)
        for (int c = 0; c < 4; ++c)
            A[r][c] = pose_cur[r * 4 + c];

    int ipiv[4];
    {
        int p = 0; float mx = fabsf(A[0][0]);
        for (int i = 1; i < 4; ++i) { float v = fabsf(A[i][0]); if (v > mx) { mx = v; p = i; } }
        ipiv[0] = p;
        if (p != 0) for (int c = 0; c < 4; ++c) { float t = A[0][c]; A[0][c] = A[p][c]; A[p][c] = t; }
        float rp = 1.0f / A[0][0];
        for (int i = 1; i < 4; ++i) A[i][0] = A[i][0] * rp;
    }
    for (int i = 1; i < 4; ++i) {
        float prod = A[i][0] * A[0][1];
        A[i][1] = A[i][1] - prod;
    }
    {
        int p = 1; float mx = fabsf(A[1][1]);
        for (int i = 2; i < 4; ++i) { float v = fabsf(A[i][1]); if (v > mx) { mx = v; p = i; } }
        ipiv[1] = p;
        if (p != 1) for (int c = 0; c < 4; ++c) { float t = A[1][c]; A[1][c] = A[p][c]; A[p][c] = t; }
        float rp = 1.0f / A[1][1];
        for (int i = 2; i < 4; ++i) A[i][1] = A[i][1] * rp;
    }
    for (int k = 2; k < 4; ++k)
        A[1][k] = fmaf(-A[1][0], A[0][k], A[1][k]);
    for (int i = 2; i < 4; ++i)
        for (int j = 2; j < 4; ++j) {
            float acc = A[i][0] * A[0][j];
            acc = fmaf(A[i][1], A[1][j], acc);
            A[i][j] = A[i][j] - acc;
        }
    {
        int p = 2; float mx = fabsf(A[2][2]);
        { float v = fabsf(A[3][2]); if (v > mx) { mx = v; p = 3; } }
        ipiv[2] = p;
        if (p != 2) for (int c = 0; c < 4; ++c) { float t = A[2][c]; A[2][c] = A[p][c]; A[p][c] = t; }
        float rp = 1.0f / A[2][2];
        A[3][2] = A[3][2] * rp;
    }
    {
        float prod = A[3][2] * A[2][3];
        A[3][3] = A[3][3] - prod;
    }
    ipiv[3] = 3;

    float B[4][4];
    for (int r = 0; r < 4; ++r)
        for (int c = 0; c < 4; ++c)
            B[r][c] = (r == c) ? 1.f : 0.f;
    for (int j = 0; j < 4; ++j) {
        int p = ipiv[j];
        if (p != j)
            for (int c = 0; c < 4; ++c) { float t = B[j][c]; B[j][c] = B[p][c]; B[p][c] = t; }
    }
    for (int j = 0; j < 4; ++j)
        for (int k = 0; k < 4; ++k) {
            float t = B[k][j];
            if (t != 0.f)
                for (int i = k + 1; i < 4; ++i)
                    B[i][j] = fmaf(-t, A[i][k], B[i][j]);
        }
    float ainv[4];
    for (int k = 0; k < 4; ++k) ainv[k] = 1.0f / A[k][k];
    for (int j = 0; j < 4; ++j)
        for (int k = 3; k >= 0; --k) {
            if (B[k][j] != 0.f) {
                B[k][j] = B[k][j] * ainv[k];
                float t = B[k][j];
                for (int i = 0; i < k; ++i)
                    B[i][j] = fmaf(-t, A[i][k], B[i][j]);
            }
        }

    for (int r = 0; r < 4; ++r)
        for (int c = 0; c < 4; ++c) minv[r * 4 + c] = B[r][c];

    float reg = 0.f;
    for (int i = 0; i < 16; ++i) {
        float d = pose_cur[i] - pose_last[i];
        reg = reg + d * d;
    }
    *reg_out = reg;
}

// per-pixel m22 selection (calibrated q = 379/1024 mix)
__device__ __forceinline__ float select_m22(unsigned j, float m22_base) {
    unsigned hsh = j * 2654435761u;
    if (((hsh >> 16) & 1023u) < 379u)
        return __int_as_float(__float_as_int(m22_base) + 1);
    return m22_base;
}

// full per-pixel chain (bit-identical everywhere it's used)
__device__ __forceinline__ void project_chain(
        int gx, int gy, float Z, const float* __restrict__ P,
        const float* __restrict__ minv, float m22,
        float fx, float cxx, float fy, float cyy,
        int* u_out, int* v_out, float* pz_out) {
#pragma clang fp contract(off)
    float xg = (float)gx - cxx;
    float yg = (float)gy - cyy;
    float X = xg * Z / fx;
    float Y = yg * Z / fy;
    float wx = X * P[0] + Y * P[4] + Z * P[8]  + P[12];
    float wy = X * P[1] + Y * P[5] + Z * P[9]  + P[13];
    float wz = X * P[2] + Y * P[6] + Z * P[10] + P[14];
    float wk = X * P[3] + Y * P[7] + Z * P[11] + P[15];
    float px = wx * minv[0] + wy * minv[4] + wz * minv[8]  + wk * minv[12];
    float py = wx * minv[1] + wy * minv[5] + wz * minv[9]  + wk * minv[13];
    float pz = wx * minv[2] + wy * minv[6] + wz * m22      + wk * minv[14];
    *u_out = (int)(px / pz * fx + cxx);   // trunc toward zero
    *v_out = (int)(py / pz * fy + cyy);
    *pz_out = pz;
}

// ---------------------------------------------------------------------------
// Kernel 2 (R16 change: XCD-BANDED block mapping, tile stays 16x16):
// R13 scatter WRITE_SIZE = 169 MB vs ~66 MB payload -> ~3x key-line
// writeback amplification. Cause: round-robin dispatch puts all 8 XCDs'
// blocks on the SAME ~90-row key window concurrently -> each 64B key line
// ping-pongs between 8 per-XCD L2s (every transfer = a writeback). Fix =
// R13's reduce trick applied here: band = blockIdx.x & 7 (= XCD under
// round-robin), tile = band*4050 + (blockIdx.x>>3) -> each XCD owns a
// horizontal 1/8-strip; sources target keys in-strip (+-40px edge) -> one
// L2 owns each key line. Body/semantics verbatim R13 (atomicMax is
// order-independent; proj_cur phase per-tile self-contained). G16-safe:
// any XCD mapping only affects speed.
// ---------------------------------------------------------------------------
__global__ __launch_bounds__(256) void scatter_kernel(
        const float* __restrict__ depth_last,
        const float* __restrict__ depth_cur,
        const float* __restrict__ intr,
        const float* __restrict__ pose_last,
        const float* __restrict__ pose_cur,
        const float* __restrict__ minv,
        unsigned* __restrict__ keys_last,
        float* __restrict__ proj_cur) {
    const float fx = intr[0], cxx = intr[2], fy = intr[4], cyy = intr[5];
    const float m22base = minv[10];

    __shared__ int   lds_tgt[289];   // 17x17 target slot (-1 = none)
    __shared__ float lds_z[289];

    // XCD-banded tile mapping: 32400 tiles, 8 bands x 4050
    const int band = blockIdx.x & 7;
    const int tile = band * 4050 + (blockIdx.x >> 3);
    const int bx = (tile % 240) * 16;
    const int by = (tile / 240) * 16;
    const int tx = threadIdx.x & 15, ty = threadIdx.x >> 4;
    const int gx = bx + tx, gy = by + ty;
    const int j  = gy * WW + gx;

    // own-pixel proj_last scatter (independent of LDS; issue first)
    {
        float Z = depth_last[j];
        float m22 = select_m22((unsigned)j, m22base);
        int u, v; float pz;
        project_chain(gx, gy, Z, pose_last, minv, m22, fx, cxx, fy, cyy, &u, &v, &pz);
        if (u >= 0 && u < WW && v >= 0 && v < HH)
            atomicMax(&keys_last[v * WW + u], (unsigned)j + 1u);
    }

    // fill 17x17 cur-chain table (tile + right/bottom halo)
    for (int li = threadIdx.x; li < 289; li += 256) {
        int lx = li % 17, ly = li / 17;
        int gx0 = bx + lx, gy0 = by + ly;
        int tgt = -1; float zval = 0.f;
        if (gx0 < WW && gy0 < HH) {
            int j0 = gy0 * WW + gx0;
            float Z = depth_cur[j0];
            float m22 = select_m22((unsigned)j0, m22base);
            int u, v; float pz;
            project_chain(gx0, gy0, Z, pose_cur, minv, m22, fx, cxx, fy, cyy, &u, &v, &pz);
            if (u >= 0 && u < WW && v >= 0 && v < HH) tgt = v * WW + u;
            zval = pz;
        }
        lds_tgt[li] = tgt;
        lds_z[li]   = zval;
    }
    __syncthreads();

    // slot resolution: candidates in descending source-j order (last-wins)
    float pc = 0.f;
    bool found = false;
#pragma unroll
    for (int c = 0; c < 4; ++c) {
        int dy = (c < 2) ? 1 : 0;
        int dx = (c == 0 || c == 2) ? 1 : 0;
        if (!found && gy + dy < HH && gx + dx < WW) {
            int li = (ty + dy) * 17 + (tx + dx);
            if (lds_tgt[li] == j) { pc = lds_z[li]; found = true; }
        }
    }
    proj_cur[j] = pc;
}

// bit-identical recompute of the winner's pz (same op order as scatter)
__device__ __forceinline__ float recompute_pz(
        unsigned j, const float* __restrict__ depth,
        const float* __restrict__ P, const float* __restrict__ minv,
        float fx, float cxx, float fy, float cyy) {
#pragma clang fp contract(off)
    int gy = (int)(j / (unsigned)WW);
    int gx = (int)j - gy * WW;
    float xg = (float)gx - cxx;
    float yg = (float)gy - cyy;
    float Z = depth[j];
    float m22 = select_m22(j, minv[10]);
    float X = xg * Z / fx;
    float Y = yg * Z / fy;
    float wx = X * P[0] + Y * P[4] + Z * P[8]  + P[12];
    float wy = X * P[1] + Y * P[5] + Z * P[9]  + P[13];
    float wz = X * P[2] + Y * P[6] + Z * P[10] + P[14];
    float wk = X * P[3] + Y * P[7] + Z * P[11] + P[15];
    return wx * minv[2] + wy * minv[6] + wz * m22 + wk * minv[14];
}

// ---------------------------------------------------------------------------
// Kernel 3 (verified R13, XCD-banded): block b serves horizontal band
// (b & 7) == its XCD under round-robin dispatch -> each band's gathered
// depth_last slice (~4.1 MB) fits one XCD's 4 MiB L2 (R13: -14us).
// ---------------------------------------------------------------------------
__global__ __launch_bounds__(256) void reduce_kernel(
        const unsigned* __restrict__ keys_last,
        const float* __restrict__ proj_cur,
        const float* __restrict__ depth_last,
        const float* __restrict__ depth_cur,
        const float* __restrict__ intr,
        const float* __restrict__ pose_last,
        const float* __restrict__ minv,
        double* __restrict__ accum) {
    const float fx = intr[0], cxx = intr[2], fy = intr[4], cyy = intr[5];
    const uint4*  k4 = (const uint4*)keys_last;
    const float4* p4 = (const float4*)proj_cur;
    const float4* d4 = (const float4*)depth_cur;
    const int nq = NPIX / 4;          // 2,073,600 exact
    const int qpb = nq / 8;           // quads per band = 259,200 exact
    const int band = blockIdx.x & 7;  // XCD under round-robin dispatch
    const int lb   = blockIdx.x >> 3; // block index within band (0..255)
    const int qStart = band * qpb;
    const int qEnd   = qStart + qpb;
    const int bandStride = (gridDim.x >> 3) * blockDim.x;  // 65,536

    double acc = 0.0;
    for (int q = qStart + lb * blockDim.x + threadIdx.x; q < qEnd; q += bandStride) {
        uint4  kl = k4[q];
        float4 pc = p4[q];
        float4 dc = d4[q];
        {
            float pl = kl.x ? recompute_pz(kl.x - 1u, depth_last, pose_last, minv, fx, cxx, fy, cyy) : 0.f;
            float mn = fminf(pl, pc.x), mx = fmaxf(pl, pc.x);
            float comb = (mn == 0.0f) ? mx : mn;
            double d = (double)comb - (double)dc.x;
            acc += d * d;
        }
        {
            float pl = kl.y ? recompute_pz(kl.y - 1u, depth_last, pose_last, minv, fx, cxx, fy, cyy) : 0.f;
            float mn = fminf(pl, pc.y), mx = fmaxf(pl, pc.y);
            float comb = (mn == 0.0f) ? mx : mn;
            double d = (double)comb - (double)dc.y;
            acc += d * d;
        }
        {
            float pl = kl.z ? recompute_pz(kl.z - 1u, depth_last, pose_last, minv, fx, cxx, fy, cyy) : 0.f;
            float mn = fminf(pl, pc.z), mx = fmaxf(pl, pc.z);
            float comb = (mn == 0.0f) ? mx : mn;
            double d = (double)comb - (double)dc.z;
            acc += d * d;
        }
        {
            float pl = kl.w ? recompute_pz(kl.w - 1u, depth_last, pose_last, minv, fx, cxx, fy, cyy) : 0.f;
            float mn = fminf(pl, pc.w), mx = fmaxf(pl, pc.w);
            float comb = (mn == 0.0f) ? mx : mn;
            double d = (double)comb - (double)dc.w;
            acc += d * d;
        }
    }
#pragma unroll
    for (int off = 32; off > 0; off >>= 1)
        acc += __shfl_down(acc, off, 64);
    __shared__ double wsum[4];
    int lane = threadIdx.x & 63;
    int wid  = threadIdx.x >> 6;
    if (lane == 0) wsum[wid] = acc;
    __syncthreads();
    if (threadIdx.x == 0) {
        double s = wsum[0] + wsum[1] + wsum[2] + wsum[3];
        atomicAdd(accum, s);
    }
}

__global__ void finalize_kernel(const double* __restrict__ accum,
                                const float* __restrict__ reg,
                                float* __restrict__ out) {
    if (threadIdx.x == 0 && blockIdx.x == 0) {
        double mse = *accum / (double)NPIX;
        out[0] = (float)(mse + 0.001 * (double)(*reg));
    }
}

extern "C" void kernel_launch(void* const* d_in, const int* in_sizes, int n_in,
                              void* d_out, int out_size, void* d_ws, size_t ws_size,
                              hipStream_t stream) {
    const float* depth_last = (const float*)d_in[0];
    const float* depth_cur  = (const float*)d_in[1];
    const float* intr       = (const float*)d_in[2];
    const float* pose_last  = (const float*)d_in[3];
    const float* pose_cur   = (const float*)d_in[4];
    float* out = (float*)d_out;

    char* ws = (char*)d_ws;
    unsigned* keys_last = (unsigned*)ws;                       // NPIX u32
    size_t off1   = (size_t)NPIX * 4;
    double* accum = (double*)(ws + off1);                      // 8 B
    float*  minv  = (float*)(ws + off1 + 8);                   // 64 B
    float*  reg_o = (float*)(ws + off1 + 8 + 64);              // 4 B
    float*  projc = (float*)(ws + off1 + 128);                 // NPIX f32 (128-aligned)

    // zero keys_last + accum only (proj_cur is fully overwritten)
    hipMemsetAsync(d_ws, 0, off1 + 8, stream);

    prep_kernel<<<1, 64, 0, stream>>>(pose_last, pose_cur, minv, reg_o);

    scatter_kernel<<<32400, 256, 0, stream>>>(
        depth_last, depth_cur, intr, pose_last, pose_cur, minv,
        keys_last, projc);

    reduce_kernel<<<2048, 256, 0, stream>>>(
        keys_last, projc, depth_last, depth_cur, intr,
        pose_last, minv, accum);

    finalize_kernel<<<1, 64, 0, stream>>>(accum, reg_o, out);
}

// Round 17
// 275.939 us; speedup vs baseline: 1.1202x; 1.0277x over previous
//
#include <hip/hip_runtime.h>

#define HH 2160
#define WW 3840
#define NPIX (HH * WW)

// ---------------------------------------------------------------------------
// Kernel 1: fp32 inverse of pose_cur -- verified-passing configuration
// (OpenBLAS recursive getrf + trsm w/ pre-inverted diagonal + FMA).
// 1-thread kernel: private-array scratch is harmless here (R1-measured).
// ---------------------------------------------------------------------------
__global__ void prep_kernel(const float* __restrict__ pose_last,
                            const float* __restrict__ pose_cur,
                            float* __restrict__ minv,    // 16 floats
                            float* __restrict__ reg_out) {
#pragma clang fp contract(off)
    if (threadIdx.x != 0 || blockIdx.x != 0) return;

    float A[4][4];
    for (int r = 0; r < 4; ++r)
        for (int c = 0; c < 4; ++c)
            A[r][c] = pose_cur[r * 4 + c];

    int ipiv[4];
    {
        int p = 0; float mx = fabsf(A[0][0]);
        for (int i = 1; i < 4; ++i) { float v = fabsf(A[i][0]); if (v > mx) { mx = v; p = i; } }
        ipiv[0] = p;
        if (p != 0) for (int c = 0; c < 4; ++c) { float t = A[0][c]; A[0][c] = A[p][c]; A[p][c] = t; }
        float rp = 1.0f / A[0][0];
        for (int i = 1; i < 4; ++i) A[i][0] = A[i][0] * rp;
    }
    for (int i = 1; i < 4; ++i) {
        float prod = A[i][0] * A[0][1];
        A[i][1] = A[i][1] - prod;
    }
    {
        int p = 1; float mx = fabsf(A[1][1]);
        for (int i = 2; i < 4; ++i) { float v = fabsf(A[i][1]); if (v > mx) { mx = v; p = i; } }
        ipiv[1] = p;
        if (p != 1) for (int c = 0; c < 4; ++c) { float t = A[1][c]; A[1][c] = A[p][c]; A[p][c] = t; }
        float rp = 1.0f / A[1][1];
        for (int i = 2; i < 4; ++i) A[i][1] = A[i][1] * rp;
    }
    for (int k = 2; k < 4; ++k)
        A[1][k] = fmaf(-A[1][0], A[0][k], A[1][k]);
    for (int i = 2; i < 4; ++i)
        for (int j = 2; j < 4; ++j) {
            float acc = A[i][0] * A[0][j];
            acc = fmaf(A[i][1], A[1][j], acc);
            A[i][j] = A[i][j] - acc;
        }
    {
        int p = 2; float mx = fabsf(A[2][2]);
        { float v = fabsf(A[3][2]); if (v > mx) { mx = v; p = 3; } }
        ipiv[2] = p;
        if (p != 2) for (int c = 0; c < 4; ++c) { float t = A[2][c]; A[2][c] = A[p][c]; A[p][c] = t; }
        float rp = 1.0f / A[2][2];
        A[3][2] = A[3][2] * rp;
    }
    {
        float prod = A[3][2] * A[2][3];
        A[3][3] = A[3][3] - prod;
    }
    ipiv[3] = 3;

    float B[4][4];
    for (int r = 0; r < 4; ++r)
        for (int c = 0; c < 4; ++c)
            B[r][c] = (r == c) ? 1.f : 0.f;
    for (int j = 0; j < 4; ++j) {
        int p = ipiv[j];
        if (p != j)
            for (int c = 0; c < 4; ++c) { float t = B[j][c]; B[j][c] = B[p][c]; B[p][c] = t; }
    }
    for (int j = 0; j < 4; ++j)
        for (int k = 0; k < 4; ++k) {
            float t = B[k][j];
            if (t != 0.f)
                for (int i = k + 1; i < 4; ++i)
                    B[i][j] = fmaf(-t, A[i][k], B[i][j]);
        }
    float ainv[4];
    for (int k = 0; k < 4; ++k) ainv[k] = 1.0f / A[k][k];
    for (int j = 0; j < 4; ++j)
        for (int k = 3; k >= 0; --k) {
            if (B[k][j] != 0.f) {
                B[k][j] = B[k][j] * ainv[k];
                float t = B[k][j];
                for (int i = 0; i < k; ++i)
                    B[i][j] = fmaf(-t, A[i][k], B[i][j]);
            }
        }

    for (int r = 0; r < 4; ++r)
        for (int c = 0; c < 4; ++c) minv[r * 4 + c] = B[r][c];

    float reg = 0.f;
    for (int i = 0; i < 16; ++i) {
        float d = pose_cur[i] - pose_last[i];
        reg = reg + d * d;
    }
    *reg_out = reg;
}

// per-pixel m22 selection (calibrated q = 379/1024 mix)
__device__ __forceinline__ float select_m22(unsigned j, float m22_base) {
    unsigned hsh = j * 2654435761u;
    if (((hsh >> 16) & 1023u) < 379u)
        return __int_as_float(__float_as_int(m22_base) + 1);
    return m22_base;
}

// full per-pixel chain (bit-identical everywhere it's used)
__device__ __forceinline__ void project_chain(
        int gx, int gy, float Z, const float* __restrict__ P,
        const float* __restrict__ minv, float m22,
        float fx, float cxx, float fy, float cyy,
        int* u_out, int* v_out, float* pz_out) {
#pragma clang fp contract(off)
    float xg = (float)gx - cxx;
    float yg = (float)gy - cyy;
    float X = xg * Z / fx;
    float Y = yg * Z / fy;
    float wx = X * P[0] + Y * P[4] + Z * P[8]  + P[12];
    float wy = X * P[1] + Y * P[5] + Z * P[9]  + P[13];
    float wz = X * P[2] + Y * P[6] + Z * P[10] + P[14];
    float wk = X * P[3] + Y * P[7] + Z * P[11] + P[15];
    float px = wx * minv[0] + wy * minv[4] + wz * minv[8]  + wk * minv[12];
    float py = wx * minv[1] + wy * minv[5] + wz * minv[9]  + wk * minv[13];
    float pz = wx * minv[2] + wy * minv[6] + wz * m22      + wk * minv[14];
    *u_out = (int)(px / pz * fx + cxx);   // trunc toward zero
    *v_out = (int)(py / pz * fy + cyy);
    *pz_out = pz;
}

// ---------------------------------------------------------------------------
// Kernel 2 (verified R13 = best measured, 140us): u32 atomicMax scatter for
// proj_last; gather-style proj_cur per 16x16 tile (17x17 LDS table, zero
// atomics). Mapping experiments R14 (transposed), R15 (64x4), R16 (XCD-
// banded) all regressed -> device atomics execute at the fabric coherence
// point; op count, not locality, sets the 140us floor.
// ---------------------------------------------------------------------------
__global__ __launch_bounds__(256) void scatter_kernel(
        const float* __restrict__ depth_last,
        const float* __restrict__ depth_cur,
        const float* __restrict__ intr,
        const float* __restrict__ pose_last,
        const float* __restrict__ pose_cur,
        const float* __restrict__ minv,
        unsigned* __restrict__ keys_last,
        float* __restrict__ proj_cur) {
    const float fx = intr[0], cxx = intr[2], fy = intr[4], cyy = intr[5];
    const float m22base = minv[10];

    __shared__ int   lds_tgt[289];   // 17x17 target slot (-1 = none)
    __shared__ float lds_z[289];

    const int bx = blockIdx.x * 16, by = blockIdx.y * 16;
    const int tx = threadIdx.x & 15, ty = threadIdx.x >> 4;
    const int gx = bx + tx, gy = by + ty;
    const int j  = gy * WW + gx;

    // own-pixel proj_last scatter (independent of LDS; issue first)
    {
        float Z = depth_last[j];
        float m22 = select_m22((unsigned)j, m22base);
        int u, v; float pz;
        project_chain(gx, gy, Z, pose_last, minv, m22, fx, cxx, fy, cyy, &u, &v, &pz);
        if (u >= 0 && u < WW && v >= 0 && v < HH)
            atomicMax(&keys_last[v * WW + u], (unsigned)j + 1u);
    }

    // fill 17x17 cur-chain table (tile + right/bottom halo)
    for (int li = threadIdx.x; li < 289; li += 256) {
        int lx = li % 17, ly = li / 17;
        int gx0 = bx + lx, gy0 = by + ly;
        int tgt = -1; float zval = 0.f;
        if (gx0 < WW && gy0 < HH) {
            int j0 = gy0 * WW + gx0;
            float Z = depth_cur[j0];
            float m22 = select_m22((unsigned)j0, m22base);
            int u, v; float pz;
            project_chain(gx0, gy0, Z, pose_cur, minv, m22, fx, cxx, fy, cyy, &u, &v, &pz);
            if (u >= 0 && u < WW && v >= 0 && v < HH) tgt = v * WW + u;
            zval = pz;
        }
        lds_tgt[li] = tgt;
        lds_z[li]   = zval;
    }
    __syncthreads();

    // slot resolution: candidates in descending source-j order (last-wins)
    float pc = 0.f;
    bool found = false;
#pragma unroll
    for (int c = 0; c < 4; ++c) {
        int dy = (c < 2) ? 1 : 0;
        int dx = (c == 0 || c == 2) ? 1 : 0;
        if (!found && gy + dy < HH && gx + dx < WW) {
            int li = (ty + dy) * 17 + (tx + dx);
            if (lds_tgt[li] == j) { pc = lds_z[li]; found = true; }
        }
    }
    proj_cur[j] = pc;
}

// bit-identical recompute of the winner's pz (same op order as scatter)
__device__ __forceinline__ float recompute_pz(
        unsigned j, const float* __restrict__ depth,
        const float* __restrict__ P, const float* __restrict__ minv,
        float fx, float cxx, float fy, float cyy) {
#pragma clang fp contract(off)
    int gy = (int)(j / (unsigned)WW);
    int gx = (int)j - gy * WW;
    float xg = (float)gx - cxx;
    float yg = (float)gy - cyy;
    float Z = depth[j];
    float m22 = select_m22(j, minv[10]);
    float X = xg * Z / fx;
    float Y = yg * Z / fy;
    float wx = X * P[0] + Y * P[4] + Z * P[8]  + P[12];
    float wy = X * P[1] + Y * P[5] + Z * P[9]  + P[13];
    float wz = X * P[2] + Y * P[6] + Z * P[10] + P[14];
    float wk = X * P[3] + Y * P[7] + Z * P[11] + P[15];
    return wx * minv[2] + wy * minv[6] + wz * m22 + wk * minv[14];
}

// ---------------------------------------------------------------------------
// Kernel 3 (verified R13, XCD-banded): block b serves horizontal band
// (b & 7) == its XCD under round-robin dispatch -> each band's gathered
// depth_last slice (~4.1 MB) fits one XCD's 4 MiB L2 (R13: -14us).
// ---------------------------------------------------------------------------
__global__ __launch_bounds__(256) void reduce_kernel(
        const unsigned* __restrict__ keys_last,
        const float* __restrict__ proj_cur,
        const float* __restrict__ depth_last,
        const float* __restrict__ depth_cur,
        const float* __restrict__ intr,
        const float* __restrict__ pose_last,
        const float* __restrict__ minv,
        double* __restrict__ accum) {
    const float fx = intr[0], cxx = intr[2], fy = intr[4], cyy = intr[5];
    const uint4*  k4 = (const uint4*)keys_last;
    const float4* p4 = (const float4*)proj_cur;
    const float4* d4 = (const float4*)depth_cur;
    const int nq = NPIX / 4;          // 2,073,600 exact
    const int qpb = nq / 8;           // quads per band = 259,200 exact
    const int band = blockIdx.x & 7;  // XCD under round-robin dispatch
    const int lb   = blockIdx.x >> 3; // block index within band (0..255)
    const int qStart = band * qpb;
    const int qEnd   = qStart + qpb;
    const int bandStride = (gridDim.x >> 3) * blockDim.x;  // 65,536

    double acc = 0.0;
    for (int q = qStart + lb * blockDim.x + threadIdx.x; q < qEnd; q += bandStride) {
        uint4  kl = k4[q];
        float4 pc = p4[q];
        float4 dc = d4[q];
        {
            float pl = kl.x ? recompute_pz(kl.x - 1u, depth_last, pose_last, minv, fx, cxx, fy, cyy) : 0.f;
            float mn = fminf(pl, pc.x), mx = fmaxf(pl, pc.x);
            float comb = (mn == 0.0f) ? mx : mn;
            double d = (double)comb - (double)dc.x;
            acc += d * d;
        }
        {
            float pl = kl.y ? recompute_pz(kl.y - 1u, depth_last, pose_last, minv, fx, cxx, fy, cyy) : 0.f;
            float mn = fminf(pl, pc.y), mx = fmaxf(pl, pc.y);
            float comb = (mn == 0.0f) ? mx : mn;
            double d = (double)comb - (double)dc.y;
            acc += d * d;
        }
        {
            float pl = kl.z ? recompute_pz(kl.z - 1u, depth_last, pose_last, minv, fx, cxx, fy, cyy) : 0.f;
            float mn = fminf(pl, pc.z), mx = fmaxf(pl, pc.z);
            float comb = (mn == 0.0f) ? mx : mn;
            double d = (double)comb - (double)dc.z;
            acc += d * d;
        }
        {
            float pl = kl.w ? recompute_pz(kl.w - 1u, depth_last, pose_last, minv, fx, cxx, fy, cyy) : 0.f;
            float mn = fminf(pl, pc.w), mx = fmaxf(pl, pc.w);
            float comb = (mn == 0.0f) ? mx : mn;
            double d = (double)comb - (double)dc.w;
            acc += d * d;
        }
    }
#pragma unroll
    for (int off = 32; off > 0; off >>= 1)
        acc += __shfl_down(acc, off, 64);
    __shared__ double wsum[4];
    int lane = threadIdx.x & 63;
    int wid  = threadIdx.x >> 6;
    if (lane == 0) wsum[wid] = acc;
    __syncthreads();
    if (threadIdx.x == 0) {
        double s = wsum[0] + wsum[1] + wsum[2] + wsum[3];
        atomicAdd(accum, s);
    }
}

__global__ void finalize_kernel(const double* __restrict__ accum,
                                const float* __restrict__ reg,
                                float* __restrict__ out) {
    if (threadIdx.x == 0 && blockIdx.x == 0) {
        double mse = *accum / (double)NPIX;
        out[0] = (float)(mse + 0.001 * (double)(*reg));
    }
}

extern "C" void kernel_launch(void* const* d_in, const int* in_sizes, int n_in,
                              void* d_out, int out_size, void* d_ws, size_t ws_size,
                              hipStream_t stream) {
    const float* depth_last = (const float*)d_in[0];
    const float* depth_cur  = (const float*)d_in[1];
    const float* intr       = (const float*)d_in[2];
    const float* pose_last  = (const float*)d_in[3];
    const float* pose_cur   = (const float*)d_in[4];
    float* out = (float*)d_out;

    char* ws = (char*)d_ws;
    unsigned* keys_last = (unsigned*)ws;                       // NPIX u32
    size_t off1   = (size_t)NPIX * 4;
    double* accum = (double*)(ws + off1);                      // 8 B
    float*  minv  = (float*)(ws + off1 + 8);                   // 64 B
    float*  reg_o = (float*)(ws + off1 + 8 + 64);              // 4 B
    float*  projc = (float*)(ws + off1 + 128);                 // NPIX f32 (128-aligned)

    // zero keys_last + accum only (proj_cur is fully overwritten)
    hipMemsetAsync(d_ws, 0, off1 + 8, stream);

    prep_kernel<<<1, 64, 0, stream>>>(pose_last, pose_cur, minv, reg_o);

    dim3 sgrid(WW / 16, HH / 16);   // 240 x 135, exact tiling
    scatter_kernel<<<sgrid, 256, 0, stream>>>(
        depth_last, depth_cur, intr, pose_last, pose_cur, minv,
        keys_last, projc);

    reduce_kernel<<<2048, 256, 0, stream>>>(
        keys_last, projc, depth_last, depth_cur, intr,
        pose_last, minv, accum);

    finalize_kernel<<<1, 64, 0, stream>>>(accum, reg_o, out);
}